// Round 12
// baseline (196.458 us; speedup 1.0000x reference)
//
#include <hip/hip_runtime.h>
#include <math.h>

#define NEG_SLOPE 0.1f

typedef __attribute__((ext_vector_type(8))) short short8;
typedef __attribute__((ext_vector_type(4))) short short4v;
typedef __attribute__((ext_vector_type(4))) float floatx4;

__device__ __forceinline__ float lrelu(float x) { return x >= 0.0f ? x : NEG_SLOPE * x; }

// fp32 -> bf16 round-to-nearest-even
__device__ __forceinline__ unsigned short f2bf(float x) {
  unsigned u = __float_as_uint(x);
  return (unsigned short)((u + 0x7fffu + ((u >> 16) & 1u)) >> 16);
}

__device__ __forceinline__ float wave_sum64(float v) {
  #pragma unroll
  for (int s = 32; s > 0; s >>= 1) v += __shfl_xor(v, s, 64);
  return v;
}

// ---------------------------------------------------------------------------
// prep stage 0: W_conv fp32 -> bf16 table (8 KB), once for all fused blocks.
// Grid 1 x 256 thr: thread t converts 16 consecutive elements.
// ---------------------------------------------------------------------------
__global__ __launch_bounds__(256) void prep_wconv(
    const float* __restrict__ W_conv, unsigned short* __restrict__ wcb) {
  const int t = threadIdx.x;
  const float* p = W_conv + t * 16;
  float4 a0 = *(const float4*)(p);
  float4 a1 = *(const float4*)(p + 4);
  float4 a2 = *(const float4*)(p + 8);
  float4 a3 = *(const float4*)(p + 12);
  short8 p0, p1;
  p0[0] = f2bf(a0.x); p0[1] = f2bf(a0.y); p0[2] = f2bf(a0.z); p0[3] = f2bf(a0.w);
  p0[4] = f2bf(a1.x); p0[5] = f2bf(a1.y); p0[6] = f2bf(a1.z); p0[7] = f2bf(a1.w);
  p1[0] = f2bf(a2.x); p1[1] = f2bf(a2.y); p1[2] = f2bf(a2.z); p1[3] = f2bf(a2.w);
  p1[4] = f2bf(a3.x); p1[5] = f2bf(a3.y); p1[6] = f2bf(a3.z); p1[7] = f2bf(a3.w);
  *(short8*)&wcb[t * 16] = p0;
  *(short8*)&wcb[t * 16 + 8] = p1;
}

// ---------------------------------------------------------------------------
// prep stage 1: dvec = mean(deg, HW). Grid 64 x 256 thr (4 blocks/batch).
// ---------------------------------------------------------------------------
__global__ __launch_bounds__(256) void prep_dvec(
    const float* __restrict__ deg, float* __restrict__ dvec_ws) {
  const int b = blockIdx.x >> 2;
  const int quarter = blockIdx.x & 3;
  const int t = threadIdx.x;
  const int half = t & 1, row = t >> 1;
  const int d = quarter * 128 + row;
  const float* p = deg + (size_t)b * 32768 + (size_t)d * 64 + half * 32;
  float4 x0 = *(const float4*)(p);
  float4 x1 = *(const float4*)(p + 4);
  float4 x2 = *(const float4*)(p + 8);
  float4 x3 = *(const float4*)(p + 12);
  float4 x4 = *(const float4*)(p + 16);
  float4 x5 = *(const float4*)(p + 20);
  float4 x6 = *(const float4*)(p + 24);
  float4 x7 = *(const float4*)(p + 28);
  float s = (x0.x + x0.y + x0.z + x0.w) + (x1.x + x1.y + x1.z + x1.w) +
            (x2.x + x2.y + x2.z + x2.w) + (x3.x + x3.y + x3.z + x3.w) +
            (x4.x + x4.y + x4.z + x4.w) + (x5.x + x5.y + x5.z + x5.w) +
            (x6.x + x6.y + x6.z + x6.w) + (x7.x + x7.y + x7.z + x7.w);
  s += __shfl_xor(s, 1, 64);
  if (half == 0) dvec_ws[b * 512 + d] = s * (1.0f / 64.0f);
}

// ---------------------------------------------------------------------------
// prep stage 2: f = dvec@W_size^T, fa = dvec@W_ac^T. Grid 128 x 256 thr.
// ---------------------------------------------------------------------------
__global__ __launch_bounds__(256) void prep_fmul(
    const float* __restrict__ W_size, const float* __restrict__ W_ac,
    const float* __restrict__ dvec_ws, float* __restrict__ f_ws,
    float* __restrict__ fa_ws) {
  const int b = blockIdx.x >> 3;
  const int g = blockIdx.x & 7;
  const int t = threadIdx.x;
  const int dot = t >> 4;   // 0..15: 0-7 -> W_size, 8-15 -> W_ac
  const int s = t & 15;     // K-slice index
  const int c = g * 8 + (dot & 7);
  const float* wr =
      (dot < 8 ? W_size + (size_t)c * 512 : W_ac + (size_t)c * 512) + s * 32;
  const float* dv = dvec_ws + b * 512 + s * 32;
  float p = 0.0f;
  #pragma unroll
  for (int k = 0; k < 8; ++k) {
    float4 w4 = *(const float4*)(wr + k * 4);
    float4 d4 = *(const float4*)(dv + k * 4);
    p += w4.x * d4.x + w4.y * d4.y + w4.z * d4.z + w4.w * d4.w;
  }
  p += __shfl_xor(p, 1, 64);
  p += __shfl_xor(p, 2, 64);
  p += __shfl_xor(p, 4, 64);
  p += __shfl_xor(p, 8, 64);
  if (s == 0) {
    if (dot < 8) f_ws[b * 64 + c] = p;
    else         fa_ws[b * 64 + c] = p;
  }
}

// ---------------------------------------------------------------------------
// prep stage 3: t1/t2 (8-wide), kern [576], att [64]. Grid 16 x 256 thr.
// ---------------------------------------------------------------------------
__global__ __launch_bounds__(256) void prep_tail(
    const float* __restrict__ W_k1, const float* __restrict__ W_k2,
    const float* __restrict__ W_du1, const float* __restrict__ W_du2,
    const float* __restrict__ f_ws, const float* __restrict__ fa_ws,
    float* __restrict__ kern_ws, float* __restrict__ att_ws) {
  const int b = blockIdx.x;
  const int t = threadIdx.x;
  __shared__ float t1s[8], t2s[8];
  const int wave = t >> 6, lane = t & 63;
  if (wave == 0) {
    float v = f_ws[b * 64 + lane];
    #pragma unroll
    for (int rr = 0; rr < 8; ++rr) {
      float p = wave_sum64(v * W_k1[rr * 64 + lane]);
      if (lane == 0) t1s[rr] = lrelu(p);
    }
  } else if (wave == 1) {
    float v = fa_ws[b * 64 + lane];
    #pragma unroll
    for (int rr = 0; rr < 8; ++rr) {
      float p = wave_sum64(v * W_du1[rr * 64 + lane]);
      if (lane == 0) t2s[rr] = lrelu(p);
    }
  }
  __syncthreads();

  for (int i = t; i < 576; i += 256) {
    float4 wa0 = *(const float4*)&W_k2[i * 8];
    float4 wa1 = *(const float4*)&W_k2[i * 8 + 4];
    kern_ws[b * 576 + i] =
        t1s[0] * wa0.x + t1s[1] * wa0.y + t1s[2] * wa0.z + t1s[3] * wa0.w +
        t1s[4] * wa1.x + t1s[5] * wa1.y + t1s[6] * wa1.z + t1s[7] * wa1.w;
  }
  if (t < 64) {
    float4 wa0 = *(const float4*)&W_du2[t * 8];
    float4 wa1 = *(const float4*)&W_du2[t * 8 + 4];
    float s = t2s[0] * wa0.x + t2s[1] * wa0.y + t2s[2] * wa0.z + t2s[3] * wa0.w +
              t2s[4] * wa1.x + t2s[5] * wa1.y + t2s[6] * wa1.z + t2s[7] * wa1.w;
    att_ws[b * 64 + t] = 1.0f / (1.0f + expf(-s));
  }
}

// ---------------------------------------------------------------------------
// fused v3: dw3x3+lrelu (fp32) + 1x1 conv (bf16 MFMA) + epilogue.
// Grid 2048 x 256 thr; one (b,h) row per block.
// Changes vs v1 (63 us):
//  * XCD-chunked swizzle: wg = (bid&7)*256 + (bid>>3). Each XCD gets a
//    contiguous (b, h-range) slab -> halo rows (h-1,h+1) and the epilogue
//    feat re-read are L2-resident instead of cross-XCD L3/HBM traffic.
//  * wt LDS + staging eliminated: W_conv pre-converted to bf16 (wcb, 8 KB,
//    L1/L2-broadcast), phase-2 B fragments load straight from global.
//    LDS 30.7 KB -> 21.2 KB -> 7 blocks/CU resident (was ~3).
// ---------------------------------------------------------------------------
__global__ __launch_bounds__(256, 6) void fused_kernel(
    const float* __restrict__ feat, const unsigned short* __restrict__ wcb,
    const float* __restrict__ b_conv, const float* __restrict__ kern_ws,
    const float* __restrict__ att_ws, float* __restrict__ out) {
  const int bid = blockIdx.x;
  const int wg = ((bid & 7) << 8) + (bid >> 3);  // bijective, 2048 % 8 == 0
  const int b = wg >> 7;
  const int h = wg & 127;

  const int t = threadIdx.x;

  __shared__ __align__(16) unsigned short zT[128 * 72];
  __shared__ float ks[576];
  __shared__ float atts[64];
  __shared__ float bcs[64];

  // ---- stage ks, atts, bcs (small) ----
  for (int i = t; i < 576; i += 256) ks[i] = kern_ws[b * 576 + i];
  if (t < 64) { atts[t] = att_ws[b * 64 + t]; bcs[t] = b_conv[t]; }
  __syncthreads();

  const size_t base_b = (size_t)b * 64 * 128 * 128;
  const int lane = t & 63, wave = t >> 6;
  const int cq = t >> 5;        // 0..7: channel quad group
  const int gg = t & 31;        // w-group, w0 = gg*4
  const int w0 = gg * 4;
  const int swz = (gg ^ (gg >> 3)) & 7;
  const float4 zf4 = {0.f, 0.f, 0.f, 0.f};

  const bool hgt0 = (h > 0), hlt = (h < 127);
  const float* fbase = feat + base_b + (size_t)h * 128 + w0;

  // ---- Phase 1: dw3x3 + lrelu -> zT (bf16, b64 writes) ----
  #pragma unroll
  for (int it = 0; it < 2; ++it) {
    const int c0 = cq * 4 + it * 32;
    float4 top[4], mid[4], bot[4];
    #pragma unroll
    for (int j = 0; j < 4; ++j) {
      const float* p = fbase + (size_t)(c0 + j) * 16384;
      mid[j] = *(const float4*)p;
      top[j] = hgt0 ? *(const float4*)(p - 128) : zf4;
      bot[j] = hlt  ? *(const float4*)(p + 128) : zf4;
    }
    unsigned short sres[4][4];
    #pragma unroll
    for (int j = 0; j < 4; ++j) {
      const float* kv = &ks[(c0 + j) * 9];
      const float k0 = kv[0], k1 = kv[1], k2 = kv[2];
      const float k3 = kv[3], k4 = kv[4], k5 = kv[5];
      const float k6 = kv[6], k7 = kv[7], k8 = kv[8];
      float a0 = 0.f, a1 = 0.f, a2 = 0.f, a3 = 0.f;
      {
        float4 m = top[j];
        float lf = __shfl(m.w, lane - 1, 64); if (gg == 0)  lf = 0.f;
        float rt = __shfl(m.x, lane + 1, 64); if (gg == 31) rt = 0.f;
        a0 += k0 * lf  + k1 * m.x + k2 * m.y;
        a1 += k0 * m.x + k1 * m.y + k2 * m.z;
        a2 += k0 * m.y + k1 * m.z + k2 * m.w;
        a3 += k0 * m.z + k1 * m.w + k2 * rt;
      }
      {
        float4 m = mid[j];
        float lf = __shfl(m.w, lane - 1, 64); if (gg == 0)  lf = 0.f;
        float rt = __shfl(m.x, lane + 1, 64); if (gg == 31) rt = 0.f;
        a0 += k3 * lf  + k4 * m.x + k5 * m.y;
        a1 += k3 * m.x + k4 * m.y + k5 * m.z;
        a2 += k3 * m.y + k4 * m.z + k5 * m.w;
        a3 += k3 * m.z + k4 * m.w + k5 * rt;
      }
      {
        float4 m = bot[j];
        float lf = __shfl(m.w, lane - 1, 64); if (gg == 0)  lf = 0.f;
        float rt = __shfl(m.x, lane + 1, 64); if (gg == 31) rt = 0.f;
        a0 += k6 * lf  + k7 * m.x + k8 * m.y;
        a1 += k6 * m.x + k7 * m.y + k8 * m.z;
        a2 += k6 * m.y + k7 * m.z + k8 * m.w;
        a3 += k6 * m.z + k7 * m.w + k8 * rt;
      }
      sres[j][0] = f2bf(lrelu(a0));
      sres[j][1] = f2bf(lrelu(a1));
      sres[j][2] = f2bf(lrelu(a2));
      sres[j][3] = f2bf(lrelu(a3));
    }
    const int chunk = (cq >> 1) + it * 4;
    const int kcs = ((chunk ^ swz) * 8) + (cq & 1) * 4;
    #pragma unroll
    for (int i = 0; i < 4; ++i) {
      short4v sv;
      sv[0] = (short)sres[0][i]; sv[1] = (short)sres[1][i];
      sv[2] = (short)sres[2][i]; sv[3] = (short)sres[3][i];
      *(short4v*)&zT[(w0 + i) * 72 + kcs] = sv;
    }
  }
  __syncthreads();

  // ---- Phase 2: 1x1 conv via MFMA (A=z -> D rows are w) + epilogue ----
  {
    const int r = lane & 15, q = lane >> 4;

    short8 az[2][2];
    #pragma unroll
    for (int wm2 = 0; wm2 < 2; ++wm2) {
      const int w = (wave * 2 + wm2) * 16 + r;
      const int sz = ((w >> 2) ^ (w >> 5)) & 7;
      #pragma unroll
      for (int ksp = 0; ksp < 2; ++ksp) {
        const int kc = (ksp * 4 + q) ^ sz;
        az[wm2][ksp] = *(const short8*)&zT[w * 72 + kc * 8];
      }
    }
    // B fragments straight from the 8 KB global bf16 table (L1/L2 broadcast)
    short8 bw[4][2];
    #pragma unroll
    for (int nt = 0; nt < 4; ++nt) {
      const int o = nt * 16 + r;
      #pragma unroll
      for (int ksp = 0; ksp < 2; ++ksp)
        bw[nt][ksp] = *(const short8*)&wcb[o * 64 + ksp * 32 + q * 8];
    }

    floatx4 acc[2][4];
    #pragma unroll
    for (int wm2 = 0; wm2 < 2; ++wm2)
      #pragma unroll
      for (int nt = 0; nt < 4; ++nt) acc[wm2][nt] = (floatx4){0.f, 0.f, 0.f, 0.f};

    #pragma unroll
    for (int wm2 = 0; wm2 < 2; ++wm2)
      #pragma unroll
      for (int nt = 0; nt < 4; ++nt)
        #pragma unroll
        for (int ksp = 0; ksp < 2; ++ksp)
          acc[wm2][nt] = __builtin_amdgcn_mfma_f32_16x16x32_bf16(
              az[wm2][ksp], bw[nt][ksp], acc[wm2][nt], 0, 0, 0);

    #pragma unroll
    for (int wm2 = 0; wm2 < 2; ++wm2) {
      const int wb = (wave * 2 + wm2) * 16 + q * 4;
      #pragma unroll
      for (int nt = 0; nt < 4; ++nt) {
        const int o = nt * 16 + r;
        const size_t off = base_b + (size_t)o * 16384 + (size_t)h * 128 + wb;
        float4 fv = *(const float4*)(feat + off);
        const float at = atts[o], bo = bcs[o];
        floatx4 a = acc[wm2][nt];
        float4 ov;
        ov.x = a[0] + bo + at * fv.x;
        ov.y = a[1] + bo + at * fv.y;
        ov.z = a[2] + bo + at * fv.z;
        ov.w = a[3] + bo + at * fv.w;
        *(float4*)(out + off) = ov;
      }
    }
  }
}

extern "C" void kernel_launch(void* const* d_in, const int* in_sizes, int n_in,
                              void* d_out, int out_size, void* d_ws, size_t ws_size,
                              hipStream_t stream) {
  const float* feat   = (const float*)d_in[0];
  const float* deg    = (const float*)d_in[1];
  const float* W_size = (const float*)d_in[2];
  const float* W_k1   = (const float*)d_in[3];
  const float* W_k2   = (const float*)d_in[4];
  const float* W_conv = (const float*)d_in[5];
  const float* b_conv = (const float*)d_in[6];
  const float* W_ac   = (const float*)d_in[7];
  const float* W_du1  = (const float*)d_in[8];
  const float* W_du2  = (const float*)d_in[9];
  float* out = (float*)d_out;

  float* kern_ws = (float*)d_ws;            // 16*576 = 9216 f
  float* att_ws  = kern_ws + 16 * 576;      // 16*64  = 1024 f
  float* dvec_ws = att_ws + 16 * 64;        // 16*512 = 8192 f
  float* f_ws    = dvec_ws + 16 * 512;      // 16*64  = 1024 f
  float* fa_ws   = f_ws + 16 * 64;          // 16*64  = 1024 f
  unsigned short* wcb = (unsigned short*)(fa_ws + 16 * 64);  // 4096 bf16 = 8 KB

  prep_wconv<<<1, 256, 0, stream>>>(W_conv, wcb);
  prep_dvec<<<64, 256, 0, stream>>>(deg, dvec_ws);
  prep_fmul<<<128, 256, 0, stream>>>(W_size, W_ac, dvec_ws, f_ws, fa_ws);
  prep_tail<<<16, 256, 0, stream>>>(W_k1, W_k2, W_du1, W_du2, f_ws, fa_ws,
                                    kern_ws, att_ws);
  fused_kernel<<<2048, 256, 0, stream>>>(feat, wcb, b_conv, kern_ws, att_ws,
                                         out);
}

// Round 13
// 187.387 us; speedup vs baseline: 1.0484x; 1.0484x over previous
//
#include <hip/hip_runtime.h>
#include <math.h>

#define NEG_SLOPE 0.1f

typedef __attribute__((ext_vector_type(8))) short short8;
typedef __attribute__((ext_vector_type(4))) short short4v;
typedef __attribute__((ext_vector_type(4))) float floatx4;

__device__ __forceinline__ float lrelu(float x) { return x >= 0.0f ? x : NEG_SLOPE * x; }

// fp32 -> bf16 round-to-nearest-even
__device__ __forceinline__ unsigned short f2bf(float x) {
  unsigned u = __float_as_uint(x);
  return (unsigned short)((u + 0x7fffu + ((u >> 16) & 1u)) >> 16);
}

__device__ __forceinline__ float wave_sum64(float v) {
  #pragma unroll
  for (int s = 32; s > 0; s >>= 1) v += __shfl_xor(v, s, 64);
  return v;
}

// ---------------------------------------------------------------------------
// prep stage 0: W_conv fp32 -> bf16 table (8 KB), once for all fused blocks.
// ---------------------------------------------------------------------------
__global__ __launch_bounds__(256) void prep_wconv(
    const float* __restrict__ W_conv, unsigned short* __restrict__ wcb) {
  const int t = threadIdx.x;
  const float* p = W_conv + t * 16;
  float4 a0 = *(const float4*)(p);
  float4 a1 = *(const float4*)(p + 4);
  float4 a2 = *(const float4*)(p + 8);
  float4 a3 = *(const float4*)(p + 12);
  short8 p0, p1;
  p0[0] = f2bf(a0.x); p0[1] = f2bf(a0.y); p0[2] = f2bf(a0.z); p0[3] = f2bf(a0.w);
  p0[4] = f2bf(a1.x); p0[5] = f2bf(a1.y); p0[6] = f2bf(a1.z); p0[7] = f2bf(a1.w);
  p1[0] = f2bf(a2.x); p1[1] = f2bf(a2.y); p1[2] = f2bf(a2.z); p1[3] = f2bf(a2.w);
  p1[4] = f2bf(a3.x); p1[5] = f2bf(a3.y); p1[6] = f2bf(a3.z); p1[7] = f2bf(a3.w);
  *(short8*)&wcb[t * 16] = p0;
  *(short8*)&wcb[t * 16 + 8] = p1;
}

// ---------------------------------------------------------------------------
// prep stage 1: dvec = mean(deg, HW). Grid 64 x 256 thr (4 blocks/batch).
// ---------------------------------------------------------------------------
__global__ __launch_bounds__(256) void prep_dvec(
    const float* __restrict__ deg, float* __restrict__ dvec_ws) {
  const int b = blockIdx.x >> 2;
  const int quarter = blockIdx.x & 3;
  const int t = threadIdx.x;
  const int half = t & 1, row = t >> 1;
  const int d = quarter * 128 + row;
  const float* p = deg + (size_t)b * 32768 + (size_t)d * 64 + half * 32;
  float4 x0 = *(const float4*)(p);
  float4 x1 = *(const float4*)(p + 4);
  float4 x2 = *(const float4*)(p + 8);
  float4 x3 = *(const float4*)(p + 12);
  float4 x4 = *(const float4*)(p + 16);
  float4 x5 = *(const float4*)(p + 20);
  float4 x6 = *(const float4*)(p + 24);
  float4 x7 = *(const float4*)(p + 28);
  float s = (x0.x + x0.y + x0.z + x0.w) + (x1.x + x1.y + x1.z + x1.w) +
            (x2.x + x2.y + x2.z + x2.w) + (x3.x + x3.y + x3.z + x3.w) +
            (x4.x + x4.y + x4.z + x4.w) + (x5.x + x5.y + x5.z + x5.w) +
            (x6.x + x6.y + x6.z + x6.w) + (x7.x + x7.y + x7.z + x7.w);
  s += __shfl_xor(s, 1, 64);
  if (half == 0) dvec_ws[b * 512 + d] = s * (1.0f / 64.0f);
}

// ---------------------------------------------------------------------------
// prep stage 2: f = dvec@W_size^T, fa = dvec@W_ac^T. Grid 128 x 256 thr.
// ---------------------------------------------------------------------------
__global__ __launch_bounds__(256) void prep_fmul(
    const float* __restrict__ W_size, const float* __restrict__ W_ac,
    const float* __restrict__ dvec_ws, float* __restrict__ f_ws,
    float* __restrict__ fa_ws) {
  const int b = blockIdx.x >> 3;
  const int g = blockIdx.x & 7;
  const int t = threadIdx.x;
  const int dot = t >> 4;   // 0..15: 0-7 -> W_size, 8-15 -> W_ac
  const int s = t & 15;     // K-slice index
  const int c = g * 8 + (dot & 7);
  const float* wr =
      (dot < 8 ? W_size + (size_t)c * 512 : W_ac + (size_t)c * 512) + s * 32;
  const float* dv = dvec_ws + b * 512 + s * 32;
  float p = 0.0f;
  #pragma unroll
  for (int k = 0; k < 8; ++k) {
    float4 w4 = *(const float4*)(wr + k * 4);
    float4 d4 = *(const float4*)(dv + k * 4);
    p += w4.x * d4.x + w4.y * d4.y + w4.z * d4.z + w4.w * d4.w;
  }
  p += __shfl_xor(p, 1, 64);
  p += __shfl_xor(p, 2, 64);
  p += __shfl_xor(p, 4, 64);
  p += __shfl_xor(p, 8, 64);
  if (s == 0) {
    if (dot < 8) f_ws[b * 64 + c] = p;
    else         fa_ws[b * 64 + c] = p;
  }
}

// ---------------------------------------------------------------------------
// prep stage 3: t1/t2 (8-wide), kern [576], att [64]. Grid 16 x 256 thr.
// ---------------------------------------------------------------------------
__global__ __launch_bounds__(256) void prep_tail(
    const float* __restrict__ W_k1, const float* __restrict__ W_k2,
    const float* __restrict__ W_du1, const float* __restrict__ W_du2,
    const float* __restrict__ f_ws, const float* __restrict__ fa_ws,
    float* __restrict__ kern_ws, float* __restrict__ att_ws) {
  const int b = blockIdx.x;
  const int t = threadIdx.x;
  __shared__ float t1s[8], t2s[8];
  const int wave = t >> 6, lane = t & 63;
  if (wave == 0) {
    float v = f_ws[b * 64 + lane];
    #pragma unroll
    for (int rr = 0; rr < 8; ++rr) {
      float p = wave_sum64(v * W_k1[rr * 64 + lane]);
      if (lane == 0) t1s[rr] = lrelu(p);
    }
  } else if (wave == 1) {
    float v = fa_ws[b * 64 + lane];
    #pragma unroll
    for (int rr = 0; rr < 8; ++rr) {
      float p = wave_sum64(v * W_du1[rr * 64 + lane]);
      if (lane == 0) t2s[rr] = lrelu(p);
    }
  }
  __syncthreads();

  for (int i = t; i < 576; i += 256) {
    float4 wa0 = *(const float4*)&W_k2[i * 8];
    float4 wa1 = *(const float4*)&W_k2[i * 8 + 4];
    kern_ws[b * 576 + i] =
        t1s[0] * wa0.x + t1s[1] * wa0.y + t1s[2] * wa0.z + t1s[3] * wa0.w +
        t1s[4] * wa1.x + t1s[5] * wa1.y + t1s[6] * wa1.z + t1s[7] * wa1.w;
  }
  if (t < 64) {
    float4 wa0 = *(const float4*)&W_du2[t * 8];
    float4 wa1 = *(const float4*)&W_du2[t * 8 + 4];
    float s = t2s[0] * wa0.x + t2s[1] * wa0.y + t2s[2] * wa0.z + t2s[3] * wa0.w +
              t2s[4] * wa1.x + t2s[5] * wa1.y + t2s[6] * wa1.z + t2s[7] * wa1.w;
    att_ws[b * 64 + t] = 1.0f / (1.0f + expf(-s));
  }
}

// ---------------------------------------------------------------------------
// fused v4: same as v3 but __launch_bounds__(256, 5) (v3's (256,6) forced a
// 40-VGPR allocation -> scratch spills: WRITE_SIZE 65.6->89.3 MB, 63->82 us.
// Phase 1 needs ~48 VGPRs of live row data; (256,5) = 102-VGPR cap, the
// bound the proven 63 us v1 used). Occupancy now LDS-limited: 7 blocks/CU.
//  * XCD-chunked swizzle kept: halo + epilogue re-reads -> per-XCD L2.
//  * wcb (global bf16 W_conv) kept: LDS 21.2 KB, no wt staging.
// ---------------------------------------------------------------------------
__global__ __launch_bounds__(256, 5) void fused_kernel(
    const float* __restrict__ feat, const unsigned short* __restrict__ wcb,
    const float* __restrict__ b_conv, const float* __restrict__ kern_ws,
    const float* __restrict__ att_ws, float* __restrict__ out) {
  const int bid = blockIdx.x;
  const int wg = ((bid & 7) << 8) + (bid >> 3);  // bijective, 2048 % 8 == 0
  const int b = wg >> 7;
  const int h = wg & 127;

  const int t = threadIdx.x;

  __shared__ __align__(16) unsigned short zT[128 * 72];
  __shared__ float ks[576];
  __shared__ float atts[64];
  __shared__ float bcs[64];

  // ---- stage ks, atts, bcs (small) ----
  for (int i = t; i < 576; i += 256) ks[i] = kern_ws[b * 576 + i];
  if (t < 64) { atts[t] = att_ws[b * 64 + t]; bcs[t] = b_conv[t]; }
  __syncthreads();

  const size_t base_b = (size_t)b * 64 * 128 * 128;
  const int lane = t & 63, wave = t >> 6;
  const int cq = t >> 5;        // 0..7: channel quad group
  const int gg = t & 31;        // w-group, w0 = gg*4
  const int w0 = gg * 4;
  const int swz = (gg ^ (gg >> 3)) & 7;
  const float4 zf4 = {0.f, 0.f, 0.f, 0.f};

  const bool hgt0 = (h > 0), hlt = (h < 127);
  const float* fbase = feat + base_b + (size_t)h * 128 + w0;

  // ---- Phase 1: dw3x3 + lrelu -> zT (bf16, b64 writes) ----
  #pragma unroll
  for (int it = 0; it < 2; ++it) {
    const int c0 = cq * 4 + it * 32;
    float4 top[4], mid[4], bot[4];
    #pragma unroll
    for (int j = 0; j < 4; ++j) {
      const float* p = fbase + (size_t)(c0 + j) * 16384;
      mid[j] = *(const float4*)p;
      top[j] = hgt0 ? *(const float4*)(p - 128) : zf4;
      bot[j] = hlt  ? *(const float4*)(p + 128) : zf4;
    }
    unsigned short sres[4][4];
    #pragma unroll
    for (int j = 0; j < 4; ++j) {
      const float* kv = &ks[(c0 + j) * 9];
      const float k0 = kv[0], k1 = kv[1], k2 = kv[2];
      const float k3 = kv[3], k4 = kv[4], k5 = kv[5];
      const float k6 = kv[6], k7 = kv[7], k8 = kv[8];
      float a0 = 0.f, a1 = 0.f, a2 = 0.f, a3 = 0.f;
      {
        float4 m = top[j];
        float lf = __shfl(m.w, lane - 1, 64); if (gg == 0)  lf = 0.f;
        float rt = __shfl(m.x, lane + 1, 64); if (gg == 31) rt = 0.f;
        a0 += k0 * lf  + k1 * m.x + k2 * m.y;
        a1 += k0 * m.x + k1 * m.y + k2 * m.z;
        a2 += k0 * m.y + k1 * m.z + k2 * m.w;
        a3 += k0 * m.z + k1 * m.w + k2 * rt;
      }
      {
        float4 m = mid[j];
        float lf = __shfl(m.w, lane - 1, 64); if (gg == 0)  lf = 0.f;
        float rt = __shfl(m.x, lane + 1, 64); if (gg == 31) rt = 0.f;
        a0 += k3 * lf  + k4 * m.x + k5 * m.y;
        a1 += k3 * m.x + k4 * m.y + k5 * m.z;
        a2 += k3 * m.y + k4 * m.z + k5 * m.w;
        a3 += k3 * m.z + k4 * m.w + k5 * rt;
      }
      {
        float4 m = bot[j];
        float lf = __shfl(m.w, lane - 1, 64); if (gg == 0)  lf = 0.f;
        float rt = __shfl(m.x, lane + 1, 64); if (gg == 31) rt = 0.f;
        a0 += k6 * lf  + k7 * m.x + k8 * m.y;
        a1 += k6 * m.x + k7 * m.y + k8 * m.z;
        a2 += k6 * m.y + k7 * m.z + k8 * m.w;
        a3 += k6 * m.z + k7 * m.w + k8 * rt;
      }
      sres[j][0] = f2bf(lrelu(a0));
      sres[j][1] = f2bf(lrelu(a1));
      sres[j][2] = f2bf(lrelu(a2));
      sres[j][3] = f2bf(lrelu(a3));
    }
    const int chunk = (cq >> 1) + it * 4;
    const int kcs = ((chunk ^ swz) * 8) + (cq & 1) * 4;
    #pragma unroll
    for (int i = 0; i < 4; ++i) {
      short4v sv;
      sv[0] = (short)sres[0][i]; sv[1] = (short)sres[1][i];
      sv[2] = (short)sres[2][i]; sv[3] = (short)sres[3][i];
      *(short4v*)&zT[(w0 + i) * 72 + kcs] = sv;
    }
  }
  __syncthreads();

  // ---- Phase 2: 1x1 conv via MFMA (A=z -> D rows are w) + epilogue ----
  {
    const int r = lane & 15, q = lane >> 4;

    short8 az[2][2];
    #pragma unroll
    for (int wm2 = 0; wm2 < 2; ++wm2) {
      const int w = (wave * 2 + wm2) * 16 + r;
      const int sz = ((w >> 2) ^ (w >> 5)) & 7;
      #pragma unroll
      for (int ksp = 0; ksp < 2; ++ksp) {
        const int kc = (ksp * 4 + q) ^ sz;
        az[wm2][ksp] = *(const short8*)&zT[w * 72 + kc * 8];
      }
    }
    // B fragments straight from the 8 KB global bf16 table (L1/L2 broadcast)
    short8 bw[4][2];
    #pragma unroll
    for (int nt = 0; nt < 4; ++nt) {
      const int o = nt * 16 + r;
      #pragma unroll
      for (int ksp = 0; ksp < 2; ++ksp)
        bw[nt][ksp] = *(const short8*)&wcb[o * 64 + ksp * 32 + q * 8];
    }

    floatx4 acc[2][4];
    #pragma unroll
    for (int wm2 = 0; wm2 < 2; ++wm2)
      #pragma unroll
      for (int nt = 0; nt < 4; ++nt) acc[wm2][nt] = (floatx4){0.f, 0.f, 0.f, 0.f};

    #pragma unroll
    for (int wm2 = 0; wm2 < 2; ++wm2)
      #pragma unroll
      for (int nt = 0; nt < 4; ++nt)
        #pragma unroll
        for (int ksp = 0; ksp < 2; ++ksp)
          acc[wm2][nt] = __builtin_amdgcn_mfma_f32_16x16x32_bf16(
              az[wm2][ksp], bw[nt][ksp], acc[wm2][nt], 0, 0, 0);

    #pragma unroll
    for (int wm2 = 0; wm2 < 2; ++wm2) {
      const int wb = (wave * 2 + wm2) * 16 + q * 4;
      #pragma unroll
      for (int nt = 0; nt < 4; ++nt) {
        const int o = nt * 16 + r;
        const size_t off = base_b + (size_t)o * 16384 + (size_t)h * 128 + wb;
        float4 fv = *(const float4*)(feat + off);
        const float at = atts[o], bo = bcs[o];
        floatx4 a = acc[wm2][nt];
        float4 ov;
        ov.x = a[0] + bo + at * fv.x;
        ov.y = a[1] + bo + at * fv.y;
        ov.z = a[2] + bo + at * fv.z;
        ov.w = a[3] + bo + at * fv.w;
        *(float4*)(out + off) = ov;
      }
    }
  }
}

extern "C" void kernel_launch(void* const* d_in, const int* in_sizes, int n_in,
                              void* d_out, int out_size, void* d_ws, size_t ws_size,
                              hipStream_t stream) {
  const float* feat   = (const float*)d_in[0];
  const float* deg    = (const float*)d_in[1];
  const float* W_size = (const float*)d_in[2];
  const float* W_k1   = (const float*)d_in[3];
  const float* W_k2   = (const float*)d_in[4];
  const float* W_conv = (const float*)d_in[5];
  const float* b_conv = (const float*)d_in[6];
  const float* W_ac   = (const float*)d_in[7];
  const float* W_du1  = (const float*)d_in[8];
  const float* W_du2  = (const float*)d_in[9];
  float* out = (float*)d_out;

  float* kern_ws = (float*)d_ws;            // 16*576 = 9216 f
  float* att_ws  = kern_ws + 16 * 576;      // 16*64  = 1024 f
  float* dvec_ws = att_ws + 16 * 64;        // 16*512 = 8192 f
  float* f_ws    = dvec_ws + 16 * 512;      // 16*64  = 1024 f
  float* fa_ws   = f_ws + 16 * 64;          // 16*64  = 1024 f
  unsigned short* wcb = (unsigned short*)(fa_ws + 16 * 64);  // 4096 bf16 = 8 KB

  prep_wconv<<<1, 256, 0, stream>>>(W_conv, wcb);
  prep_dvec<<<64, 256, 0, stream>>>(deg, dvec_ws);
  prep_fmul<<<128, 256, 0, stream>>>(W_size, W_ac, dvec_ws, f_ws, fa_ws);
  prep_tail<<<16, 256, 0, stream>>>(W_k1, W_k2, W_du1, W_du2, f_ws, fa_ws,
                                    kern_ws, att_ws);
  fused_kernel<<<2048, 256, 0, stream>>>(feat, wcb, b_conv, kern_ws, att_ws,
                                         out);
}

// Round 14
// 180.870 us; speedup vs baseline: 1.0862x; 1.0360x over previous
//
#include <hip/hip_runtime.h>
#include <math.h>

#define NEG_SLOPE 0.1f

typedef __attribute__((ext_vector_type(8))) short short8;
typedef __attribute__((ext_vector_type(4))) short short4v;
typedef __attribute__((ext_vector_type(4))) float floatx4;

__device__ __forceinline__ float lrelu(float x) { return x >= 0.0f ? x : NEG_SLOPE * x; }

// fp32 -> bf16 round-to-nearest-even
__device__ __forceinline__ unsigned short f2bf(float x) {
  unsigned u = __float_as_uint(x);
  return (unsigned short)((u + 0x7fffu + ((u >> 16) & 1u)) >> 16);
}

__device__ __forceinline__ float wave_sum64(float v) {
  #pragma unroll
  for (int s = 32; s > 0; s >>= 1) v += __shfl_xor(v, s, 64);
  return v;
}

// ---------------------------------------------------------------------------
// prep stage 1: dvec = mean(deg, HW). Grid 64 x 256 thr (4 blocks/batch).
// ---------------------------------------------------------------------------
__global__ __launch_bounds__(256) void prep_dvec(
    const float* __restrict__ deg, float* __restrict__ dvec_ws) {
  const int b = blockIdx.x >> 2;
  const int quarter = blockIdx.x & 3;
  const int t = threadIdx.x;
  const int half = t & 1, row = t >> 1;
  const int d = quarter * 128 + row;
  const float* p = deg + (size_t)b * 32768 + (size_t)d * 64 + half * 32;
  float4 x0 = *(const float4*)(p);
  float4 x1 = *(const float4*)(p + 4);
  float4 x2 = *(const float4*)(p + 8);
  float4 x3 = *(const float4*)(p + 12);
  float4 x4 = *(const float4*)(p + 16);
  float4 x5 = *(const float4*)(p + 20);
  float4 x6 = *(const float4*)(p + 24);
  float4 x7 = *(const float4*)(p + 28);
  float s = (x0.x + x0.y + x0.z + x0.w) + (x1.x + x1.y + x1.z + x1.w) +
            (x2.x + x2.y + x2.z + x2.w) + (x3.x + x3.y + x3.z + x3.w) +
            (x4.x + x4.y + x4.z + x4.w) + (x5.x + x5.y + x5.z + x5.w) +
            (x6.x + x6.y + x6.z + x6.w) + (x7.x + x7.y + x7.z + x7.w);
  s += __shfl_xor(s, 1, 64);
  if (half == 0) dvec_ws[b * 512 + d] = s * (1.0f / 64.0f);
}

// ---------------------------------------------------------------------------
// prep stage 2: f = dvec@W_size^T, fa = dvec@W_ac^T. Grid 128 x 256 thr.
// ---------------------------------------------------------------------------
__global__ __launch_bounds__(256) void prep_fmul(
    const float* __restrict__ W_size, const float* __restrict__ W_ac,
    const float* __restrict__ dvec_ws, float* __restrict__ f_ws,
    float* __restrict__ fa_ws) {
  const int b = blockIdx.x >> 3;
  const int g = blockIdx.x & 7;
  const int t = threadIdx.x;
  const int dot = t >> 4;   // 0..15: 0-7 -> W_size, 8-15 -> W_ac
  const int s = t & 15;     // K-slice index
  const int c = g * 8 + (dot & 7);
  const float* wr =
      (dot < 8 ? W_size + (size_t)c * 512 : W_ac + (size_t)c * 512) + s * 32;
  const float* dv = dvec_ws + b * 512 + s * 32;
  float p = 0.0f;
  #pragma unroll
  for (int k = 0; k < 8; ++k) {
    float4 w4 = *(const float4*)(wr + k * 4);
    float4 d4 = *(const float4*)(dv + k * 4);
    p += w4.x * d4.x + w4.y * d4.y + w4.z * d4.z + w4.w * d4.w;
  }
  p += __shfl_xor(p, 1, 64);
  p += __shfl_xor(p, 2, 64);
  p += __shfl_xor(p, 4, 64);
  p += __shfl_xor(p, 8, 64);
  if (s == 0) {
    if (dot < 8) f_ws[b * 64 + c] = p;
    else         fa_ws[b * 64 + c] = p;
  }
}

// ---------------------------------------------------------------------------
// prep stage 3: t1/t2 (8-wide), kern [576], att [64]. Grid 16 x 256 thr.
// ---------------------------------------------------------------------------
__global__ __launch_bounds__(256) void prep_tail(
    const float* __restrict__ W_k1, const float* __restrict__ W_k2,
    const float* __restrict__ W_du1, const float* __restrict__ W_du2,
    const float* __restrict__ f_ws, const float* __restrict__ fa_ws,
    float* __restrict__ kern_ws, float* __restrict__ att_ws) {
  const int b = blockIdx.x;
  const int t = threadIdx.x;
  __shared__ float t1s[8], t2s[8];
  const int wave = t >> 6, lane = t & 63;
  if (wave == 0) {
    float v = f_ws[b * 64 + lane];
    #pragma unroll
    for (int rr = 0; rr < 8; ++rr) {
      float p = wave_sum64(v * W_k1[rr * 64 + lane]);
      if (lane == 0) t1s[rr] = lrelu(p);
    }
  } else if (wave == 1) {
    float v = fa_ws[b * 64 + lane];
    #pragma unroll
    for (int rr = 0; rr < 8; ++rr) {
      float p = wave_sum64(v * W_du1[rr * 64 + lane]);
      if (lane == 0) t2s[rr] = lrelu(p);
    }
  }
  __syncthreads();

  for (int i = t; i < 576; i += 256) {
    float4 wa0 = *(const float4*)&W_k2[i * 8];
    float4 wa1 = *(const float4*)&W_k2[i * 8 + 4];
    kern_ws[b * 576 + i] =
        t1s[0] * wa0.x + t1s[1] * wa0.y + t1s[2] * wa0.z + t1s[3] * wa0.w +
        t1s[4] * wa1.x + t1s[5] * wa1.y + t1s[6] * wa1.z + t1s[7] * wa1.w;
  }
  if (t < 64) {
    float4 wa0 = *(const float4*)&W_du2[t * 8];
    float4 wa1 = *(const float4*)&W_du2[t * 8 + 4];
    float s = t2s[0] * wa0.x + t2s[1] * wa0.y + t2s[2] * wa0.z + t2s[3] * wa0.w +
              t2s[4] * wa1.x + t2s[5] * wa1.y + t2s[6] * wa1.z + t2s[7] * wa1.w;
    att_ws[b * 64 + t] = 1.0f / (1.0f + expf(-s));
  }
}

// ---------------------------------------------------------------------------
// fused v5 = EXACT round-3 v1 (63 us: wt LDS staging, (256,5)) + ONE diff:
// the XCD-chunked wg swizzle. Single-variable test of the swizzle.
// Round-13 evidence: swizzle+wcb bundle -> FETCH 118->43 MB (swizzle works
// mechanically) but 63->70.5 us; prime suspect for the time regression is
// wcb's phase-2 global bw loads on the critical path (this kernel reverts
// them to LDS). If this lands <=63 us: keep swizzle, attack phase-2 next.
// If ~70 us: swizzle itself regresses -> revert to pure v1.
// ---------------------------------------------------------------------------
__global__ __launch_bounds__(256, 5) void fused_kernel(
    const float* __restrict__ feat, const float* __restrict__ W_conv,
    const float* __restrict__ b_conv, const float* __restrict__ kern_ws,
    const float* __restrict__ att_ws, float* __restrict__ out) {
  const int bid = blockIdx.x;
  const int wg = ((bid & 7) << 8) + (bid >> 3);  // bijective, 2048 % 8 == 0
  const int b = wg >> 7;
  const int h = wg & 127;

  const int t = threadIdx.x;

  __shared__ __align__(16) unsigned short zT[128 * 72];
  __shared__ __align__(16) unsigned short wt[64 * 72];
  __shared__ float ks[576];
  __shared__ float atts[64];
  __shared__ float bcs[64];

  // ---- stage wt (bf16, swizzled), ks, atts, bcs ----
  {
    const int o = t >> 2;
    const int c0 = (t & 3) * 16;
    const float* wp = W_conv + o * 64 + c0;
    float4 a0 = *(const float4*)(wp);
    float4 a1 = *(const float4*)(wp + 4);
    float4 a2 = *(const float4*)(wp + 8);
    float4 a3 = *(const float4*)(wp + 12);
    const int sw = ((o >> 2) ^ (o >> 5)) & 7;
    short8 p0, p1;
    p0[0] = f2bf(a0.x); p0[1] = f2bf(a0.y); p0[2] = f2bf(a0.z); p0[3] = f2bf(a0.w);
    p0[4] = f2bf(a1.x); p0[5] = f2bf(a1.y); p0[6] = f2bf(a1.z); p0[7] = f2bf(a1.w);
    p1[0] = f2bf(a2.x); p1[1] = f2bf(a2.y); p1[2] = f2bf(a2.z); p1[3] = f2bf(a2.w);
    p1[4] = f2bf(a3.x); p1[5] = f2bf(a3.y); p1[6] = f2bf(a3.z); p1[7] = f2bf(a3.w);
    const int kc0 = ((c0 >> 3) + 0) ^ sw;
    const int kc1 = ((c0 >> 3) + 1) ^ sw;
    *(short8*)&wt[o * 72 + kc0 * 8] = p0;
    *(short8*)&wt[o * 72 + kc1 * 8] = p1;
  }
  for (int i = t; i < 576; i += 256) ks[i] = kern_ws[b * 576 + i];
  if (t < 64) { atts[t] = att_ws[b * 64 + t]; bcs[t] = b_conv[t]; }
  __syncthreads();

  const size_t base_b = (size_t)b * 64 * 128 * 128;
  const int lane = t & 63, wave = t >> 6;
  const int cq = t >> 5;        // 0..7: channel quad group
  const int gg = t & 31;        // w-group, w0 = gg*4
  const int w0 = gg * 4;
  const int swz = (gg ^ (gg >> 3)) & 7;
  const float4 zf4 = {0.f, 0.f, 0.f, 0.f};

  const bool hgt0 = (h > 0), hlt = (h < 127);
  const float* fbase = feat + base_b + (size_t)h * 128 + w0;

  // ---- Phase 1: dw3x3 + lrelu -> zT (bf16, b64 writes) ----
  #pragma unroll
  for (int it = 0; it < 2; ++it) {
    const int c0 = cq * 4 + it * 32;
    float4 top[4], mid[4], bot[4];
    #pragma unroll
    for (int j = 0; j < 4; ++j) {
      const float* p = fbase + (size_t)(c0 + j) * 16384;
      mid[j] = *(const float4*)p;
      top[j] = hgt0 ? *(const float4*)(p - 128) : zf4;
      bot[j] = hlt  ? *(const float4*)(p + 128) : zf4;
    }
    unsigned short sres[4][4];
    #pragma unroll
    for (int j = 0; j < 4; ++j) {
      const float* kv = &ks[(c0 + j) * 9];
      const float k0 = kv[0], k1 = kv[1], k2 = kv[2];
      const float k3 = kv[3], k4 = kv[4], k5 = kv[5];
      const float k6 = kv[6], k7 = kv[7], k8 = kv[8];
      float a0 = 0.f, a1 = 0.f, a2 = 0.f, a3 = 0.f;
      {
        float4 m = top[j];
        float lf = __shfl(m.w, lane - 1, 64); if (gg == 0)  lf = 0.f;
        float rt = __shfl(m.x, lane + 1, 64); if (gg == 31) rt = 0.f;
        a0 += k0 * lf  + k1 * m.x + k2 * m.y;
        a1 += k0 * m.x + k1 * m.y + k2 * m.z;
        a2 += k0 * m.y + k1 * m.z + k2 * m.w;
        a3 += k0 * m.z + k1 * m.w + k2 * rt;
      }
      {
        float4 m = mid[j];
        float lf = __shfl(m.w, lane - 1, 64); if (gg == 0)  lf = 0.f;
        float rt = __shfl(m.x, lane + 1, 64); if (gg == 31) rt = 0.f;
        a0 += k3 * lf  + k4 * m.x + k5 * m.y;
        a1 += k3 * m.x + k4 * m.y + k5 * m.z;
        a2 += k3 * m.y + k4 * m.z + k5 * m.w;
        a3 += k3 * m.z + k4 * m.w + k5 * rt;
      }
      {
        float4 m = bot[j];
        float lf = __shfl(m.w, lane - 1, 64); if (gg == 0)  lf = 0.f;
        float rt = __shfl(m.x, lane + 1, 64); if (gg == 31) rt = 0.f;
        a0 += k6 * lf  + k7 * m.x + k8 * m.y;
        a1 += k6 * m.x + k7 * m.y + k8 * m.z;
        a2 += k6 * m.y + k7 * m.z + k8 * m.w;
        a3 += k6 * m.z + k7 * m.w + k8 * rt;
      }
      sres[j][0] = f2bf(lrelu(a0));
      sres[j][1] = f2bf(lrelu(a1));
      sres[j][2] = f2bf(lrelu(a2));
      sres[j][3] = f2bf(lrelu(a3));
    }
    const int chunk = (cq >> 1) + it * 4;
    const int kcs = ((chunk ^ swz) * 8) + (cq & 1) * 4;
    #pragma unroll
    for (int i = 0; i < 4; ++i) {
      short4v sv;
      sv[0] = (short)sres[0][i]; sv[1] = (short)sres[1][i];
      sv[2] = (short)sres[2][i]; sv[3] = (short)sres[3][i];
      *(short4v*)&zT[(w0 + i) * 72 + kcs] = sv;
    }
  }
  __syncthreads();

  // ---- Phase 2: 1x1 conv via MFMA (A=z -> D rows are w) + epilogue ----
  {
    const int r = lane & 15, q = lane >> 4;

    short8 az[2][2];
    #pragma unroll
    for (int wm2 = 0; wm2 < 2; ++wm2) {
      const int w = (wave * 2 + wm2) * 16 + r;
      const int sz = ((w >> 2) ^ (w >> 5)) & 7;
      #pragma unroll
      for (int ksp = 0; ksp < 2; ++ksp) {
        const int kc = (ksp * 4 + q) ^ sz;
        az[wm2][ksp] = *(const short8*)&zT[w * 72 + kc * 8];
      }
    }
    short8 bw[4][2];
    #pragma unroll
    for (int nt = 0; nt < 4; ++nt) {
      const int o = nt * 16 + r;
      const int so = ((o >> 2) ^ (o >> 5)) & 7;
      #pragma unroll
      for (int ksp = 0; ksp < 2; ++ksp) {
        const int kc = (ksp * 4 + q) ^ so;
        bw[nt][ksp] = *(const short8*)&wt[o * 72 + kc * 8];
      }
    }

    floatx4 acc[2][4];
    #pragma unroll
    for (int wm2 = 0; wm2 < 2; ++wm2)
      #pragma unroll
      for (int nt = 0; nt < 4; ++nt) acc[wm2][nt] = (floatx4){0.f, 0.f, 0.f, 0.f};

    #pragma unroll
    for (int wm2 = 0; wm2 < 2; ++wm2)
      #pragma unroll
      for (int nt = 0; nt < 4; ++nt)
        #pragma unroll
        for (int ksp = 0; ksp < 2; ++ksp)
          acc[wm2][nt] = __builtin_amdgcn_mfma_f32_16x16x32_bf16(
              az[wm2][ksp], bw[nt][ksp], acc[wm2][nt], 0, 0, 0);

    #pragma unroll
    for (int wm2 = 0; wm2 < 2; ++wm2) {
      const int wb = (wave * 2 + wm2) * 16 + q * 4;
      #pragma unroll
      for (int nt = 0; nt < 4; ++nt) {
        const int o = nt * 16 + r;
        const size_t off = base_b + (size_t)o * 16384 + (size_t)h * 128 + wb;
        float4 fv = *(const float4*)(feat + off);
        const float at = atts[o], bo = bcs[o];
        floatx4 a = acc[wm2][nt];
        float4 ov;
        ov.x = a[0] + bo + at * fv.x;
        ov.y = a[1] + bo + at * fv.y;
        ov.z = a[2] + bo + at * fv.z;
        ov.w = a[3] + bo + at * fv.w;
        *(float4*)(out + off) = ov;
      }
    }
  }
}

extern "C" void kernel_launch(void* const* d_in, const int* in_sizes, int n_in,
                              void* d_out, int out_size, void* d_ws, size_t ws_size,
                              hipStream_t stream) {
  const float* feat   = (const float*)d_in[0];
  const float* deg    = (const float*)d_in[1];
  const float* W_size = (const float*)d_in[2];
  const float* W_k1   = (const float*)d_in[3];
  const float* W_k2   = (const float*)d_in[4];
  const float* W_conv = (const float*)d_in[5];
  const float* b_conv = (const float*)d_in[6];
  const float* W_ac   = (const float*)d_in[7];
  const float* W_du1  = (const float*)d_in[8];
  const float* W_du2  = (const float*)d_in[9];
  float* out = (float*)d_out;

  float* kern_ws = (float*)d_ws;            // 16*576 = 9216 f
  float* att_ws  = kern_ws + 16 * 576;      // 16*64  = 1024 f
  float* dvec_ws = att_ws + 16 * 64;        // 16*512 = 8192 f
  float* f_ws    = dvec_ws + 16 * 512;      // 16*64  = 1024 f
  float* fa_ws   = f_ws + 16 * 64;          // 16*64  = 1024 f

  prep_dvec<<<64, 256, 0, stream>>>(deg, dvec_ws);
  prep_fmul<<<128, 256, 0, stream>>>(W_size, W_ac, dvec_ws, f_ws, fa_ws);
  prep_tail<<<16, 256, 0, stream>>>(W_k1, W_k2, W_du1, W_du2, f_ws, fa_ws,
                                    kern_ws, att_ws);
  fused_kernel<<<2048, 256, 0, stream>>>(feat, W_conv, b_conv, kern_ws, att_ws,
                                         out);
}

// Round 17
// 176.164 us; speedup vs baseline: 1.1152x; 1.0267x over previous
//
#include <hip/hip_runtime.h>
#include <math.h>

#define NEG_SLOPE 0.1f

typedef __attribute__((ext_vector_type(8))) short short8;
typedef __attribute__((ext_vector_type(4))) short short4v;
typedef __attribute__((ext_vector_type(4))) float floatx4;

__device__ __forceinline__ float lrelu(float x) { return x >= 0.0f ? x : NEG_SLOPE * x; }

// fp32 -> bf16 round-to-nearest-even
__device__ __forceinline__ unsigned short f2bf(float x) {
  unsigned u = __float_as_uint(x);
  return (unsigned short)((u + 0x7fffu + ((u >> 16) & 1u)) >> 16);
}

__device__ __forceinline__ float wave_sum64(float v) {
  #pragma unroll
  for (int s = 32; s > 0; s >>= 1) v += __shfl_xor(v, s, 64);
  return v;
}

// ---------------------------------------------------------------------------
// prep stage 1: dvec = mean(deg, HW). Grid 64 x 256 thr (4 blocks/batch).
// ---------------------------------------------------------------------------
__global__ __launch_bounds__(256) void prep_dvec(
    const float* __restrict__ deg, float* __restrict__ dvec_ws) {
  const int b = blockIdx.x >> 2;
  const int quarter = blockIdx.x & 3;
  const int t = threadIdx.x;
  const int half = t & 1, row = t >> 1;
  const int d = quarter * 128 + row;
  const float* p = deg + (size_t)b * 32768 + (size_t)d * 64 + half * 32;
  float4 x0 = *(const float4*)(p);
  float4 x1 = *(const float4*)(p + 4);
  float4 x2 = *(const float4*)(p + 8);
  float4 x3 = *(const float4*)(p + 12);
  float4 x4 = *(const float4*)(p + 16);
  float4 x5 = *(const float4*)(p + 20);
  float4 x6 = *(const float4*)(p + 24);
  float4 x7 = *(const float4*)(p + 28);
  float s = (x0.x + x0.y + x0.z + x0.w) + (x1.x + x1.y + x1.z + x1.w) +
            (x2.x + x2.y + x2.z + x2.w) + (x3.x + x3.y + x3.z + x3.w) +
            (x4.x + x4.y + x4.z + x4.w) + (x5.x + x5.y + x5.z + x5.w) +
            (x6.x + x6.y + x6.z + x6.w) + (x7.x + x7.y + x7.z + x7.w);
  s += __shfl_xor(s, 1, 64);
  if (half == 0) dvec_ws[b * 512 + d] = s * (1.0f / 64.0f);
}

// ---------------------------------------------------------------------------
// prep stage 2: f = dvec@W_size^T, fa = dvec@W_ac^T. Grid 128 x 256 thr.
// ---------------------------------------------------------------------------
__global__ __launch_bounds__(256) void prep_fmul(
    const float* __restrict__ W_size, const float* __restrict__ W_ac,
    const float* __restrict__ dvec_ws, float* __restrict__ f_ws,
    float* __restrict__ fa_ws) {
  const int b = blockIdx.x >> 3;
  const int g = blockIdx.x & 7;
  const int t = threadIdx.x;
  const int dot = t >> 4;   // 0..15: 0-7 -> W_size, 8-15 -> W_ac
  const int s = t & 15;     // K-slice index
  const int c = g * 8 + (dot & 7);
  const float* wr =
      (dot < 8 ? W_size + (size_t)c * 512 : W_ac + (size_t)c * 512) + s * 32;
  const float* dv = dvec_ws + b * 512 + s * 32;
  float p = 0.0f;
  #pragma unroll
  for (int k = 0; k < 8; ++k) {
    float4 w4 = *(const float4*)(wr + k * 4);
    float4 d4 = *(const float4*)(dv + k * 4);
    p += w4.x * d4.x + w4.y * d4.y + w4.z * d4.z + w4.w * d4.w;
  }
  p += __shfl_xor(p, 1, 64);
  p += __shfl_xor(p, 2, 64);
  p += __shfl_xor(p, 4, 64);
  p += __shfl_xor(p, 8, 64);
  if (s == 0) {
    if (dot < 8) f_ws[b * 64 + c] = p;
    else         fa_ws[b * 64 + c] = p;
  }
}

// ---------------------------------------------------------------------------
// prep stage 3: t1/t2 (8-wide), kern [576], att [64]. Grid 16 x 256 thr.
// ---------------------------------------------------------------------------
__global__ __launch_bounds__(256) void prep_tail(
    const float* __restrict__ W_k1, const float* __restrict__ W_k2,
    const float* __restrict__ W_du1, const float* __restrict__ W_du2,
    const float* __restrict__ f_ws, const float* __restrict__ fa_ws,
    float* __restrict__ kern_ws, float* __restrict__ att_ws) {
  const int b = blockIdx.x;
  const int t = threadIdx.x;
  __shared__ float t1s[8], t2s[8];
  const int wave = t >> 6, lane = t & 63;
  if (wave == 0) {
    float v = f_ws[b * 64 + lane];
    #pragma unroll
    for (int rr = 0; rr < 8; ++rr) {
      float p = wave_sum64(v * W_k1[rr * 64 + lane]);
      if (lane == 0) t1s[rr] = lrelu(p);
    }
  } else if (wave == 1) {
    float v = fa_ws[b * 64 + lane];
    #pragma unroll
    for (int rr = 0; rr < 8; ++rr) {
      float p = wave_sum64(v * W_du1[rr * 64 + lane]);
      if (lane == 0) t2s[rr] = lrelu(p);
    }
  }
  __syncthreads();

  for (int i = t; i < 576; i += 256) {
    float4 wa0 = *(const float4*)&W_k2[i * 8];
    float4 wa1 = *(const float4*)&W_k2[i * 8 + 4];
    kern_ws[b * 576 + i] =
        t1s[0] * wa0.x + t1s[1] * wa0.y + t1s[2] * wa0.z + t1s[3] * wa0.w +
        t1s[4] * wa1.x + t1s[5] * wa1.y + t1s[6] * wa1.z + t1s[7] * wa1.w;
  }
  if (t < 64) {
    float4 wa0 = *(const float4*)&W_du2[t * 8];
    float4 wa1 = *(const float4*)&W_du2[t * 8 + 4];
    float s = t2s[0] * wa0.x + t2s[1] * wa0.y + t2s[2] * wa0.z + t2s[3] * wa0.w +
              t2s[4] * wa1.x + t2s[5] * wa1.y + t2s[6] * wa1.z + t2s[7] * wa1.w;
    att_ws[b * 64 + t] = 1.0f / (1.0f + expf(-s));
  }
}

// ---------------------------------------------------------------------------
// fused v6: v1 semantics (no swizzle, wt in LDS) restructured to 512-thread
// blocks (8 waves). Phase 1 is ONE pass/thread (4ch x 4w; v1 did two) ->
// per-wave critical path halves; 4 blocks x 8 waves = 32 waves/CU possible
// (v1 measured ~12). Phase 2: 1 w-tile/wave, 8 MFMA/wave. Same arithmetic,
// same LDS layout/swizzle, same numerics as the 63-us v1.
// ---------------------------------------------------------------------------
__global__ __launch_bounds__(512, 4) void fused_kernel(
    const float* __restrict__ feat, const float* __restrict__ W_conv,
    const float* __restrict__ b_conv, const float* __restrict__ kern_ws,
    const float* __restrict__ att_ws, float* __restrict__ out) {
  const int bid = blockIdx.x;
  const int b = bid >> 7;
  const int h = bid & 127;

  const int t = threadIdx.x;

  __shared__ __align__(16) unsigned short zT[128 * 72];
  __shared__ __align__(16) unsigned short wt[64 * 72];
  __shared__ float ks[576];
  __shared__ float atts[64];
  __shared__ float bcs[64];

  // ---- stage wt (bf16, swizzled): 512 thr, one short8 each ----
  {
    const int o = t >> 3;         // 0..63
    const int e8 = t & 7;         // channel octet 0..7
    const float* wp = W_conv + o * 64 + e8 * 8;
    float4 a0 = *(const float4*)(wp);
    float4 a1 = *(const float4*)(wp + 4);
    const int sw = ((o >> 2) ^ (o >> 5)) & 7;
    short8 p0;
    p0[0] = f2bf(a0.x); p0[1] = f2bf(a0.y); p0[2] = f2bf(a0.z); p0[3] = f2bf(a0.w);
    p0[4] = f2bf(a1.x); p0[5] = f2bf(a1.y); p0[6] = f2bf(a1.z); p0[7] = f2bf(a1.w);
    const int kc = e8 ^ sw;
    *(short8*)&wt[o * 72 + kc * 8] = p0;
  }
  for (int i = t; i < 576; i += 512) ks[i] = kern_ws[b * 576 + i];
  if (t < 64) { atts[t] = att_ws[b * 64 + t]; bcs[t] = b_conv[t]; }
  __syncthreads();

  const size_t base_b = (size_t)b * 64 * 128 * 128;
  const int lane = t & 63, wave = t >> 6;
  const int cq = t >> 5;        // 0..15: channel quad group
  const int gg = t & 31;        // w-group, w0 = gg*4
  const int w0 = gg * 4;
  const int swz = (gg ^ (gg >> 3)) & 7;
  const float4 zf4 = {0.f, 0.f, 0.f, 0.f};

  const bool hgt0 = (h > 0), hlt = (h < 127);
  const float* fbase = feat + base_b + (size_t)h * 128 + w0;

  // ---- Phase 1: dw3x3 + lrelu -> zT (single pass: 4 ch x 4 w / thread) ----
  {
    const int c0 = cq * 4;
    float4 top[4], mid[4], bot[4];
    #pragma unroll
    for (int j = 0; j < 4; ++j) {
      const float* p = fbase + (size_t)(c0 + j) * 16384;
      mid[j] = *(const float4*)p;
      top[j] = hgt0 ? *(const float4*)(p - 128) : zf4;
      bot[j] = hlt  ? *(const float4*)(p + 128) : zf4;
    }
    unsigned short sres[4][4];
    #pragma unroll
    for (int j = 0; j < 4; ++j) {
      const float* kv = &ks[(c0 + j) * 9];
      const float k0 = kv[0], k1 = kv[1], k2 = kv[2];
      const float k3 = kv[3], k4 = kv[4], k5 = kv[5];
      const float k6 = kv[6], k7 = kv[7], k8 = kv[8];
      float a0 = 0.f, a1 = 0.f, a2 = 0.f, a3 = 0.f;
      {
        float4 m = top[j];
        float lf = __shfl(m.w, lane - 1, 64); if (gg == 0)  lf = 0.f;
        float rt = __shfl(m.x, lane + 1, 64); if (gg == 31) rt = 0.f;
        a0 += k0 * lf  + k1 * m.x + k2 * m.y;
        a1 += k0 * m.x + k1 * m.y + k2 * m.z;
        a2 += k0 * m.y + k1 * m.z + k2 * m.w;
        a3 += k0 * m.z + k1 * m.w + k2 * rt;
      }
      {
        float4 m = mid[j];
        float lf = __shfl(m.w, lane - 1, 64); if (gg == 0)  lf = 0.f;
        float rt = __shfl(m.x, lane + 1, 64); if (gg == 31) rt = 0.f;
        a0 += k3 * lf  + k4 * m.x + k5 * m.y;
        a1 += k3 * m.x + k4 * m.y + k5 * m.z;
        a2 += k3 * m.y + k4 * m.z + k5 * m.w;
        a3 += k3 * m.z + k4 * m.w + k5 * rt;
      }
      {
        float4 m = bot[j];
        float lf = __shfl(m.w, lane - 1, 64); if (gg == 0)  lf = 0.f;
        float rt = __shfl(m.x, lane + 1, 64); if (gg == 31) rt = 0.f;
        a0 += k6 * lf  + k7 * m.x + k8 * m.y;
        a1 += k6 * m.x + k7 * m.y + k8 * m.z;
        a2 += k6 * m.y + k7 * m.z + k8 * m.w;
        a3 += k6 * m.z + k7 * m.w + k8 * rt;
      }
      sres[j][0] = f2bf(lrelu(a0));
      sres[j][1] = f2bf(lrelu(a1));
      sres[j][2] = f2bf(lrelu(a2));
      sres[j][3] = f2bf(lrelu(a3));
    }
    const int chunk = cq >> 1;                       // 0..7
    const int kcs = ((chunk ^ swz) * 8) + (cq & 1) * 4;
    #pragma unroll
    for (int i = 0; i < 4; ++i) {
      short4v sv;
      sv[0] = (short)sres[0][i]; sv[1] = (short)sres[1][i];
      sv[2] = (short)sres[2][i]; sv[3] = (short)sres[3][i];
      *(short4v*)&zT[(w0 + i) * 72 + kcs] = sv;
    }
  }
  __syncthreads();

  // ---- Phase 2: 1x1 conv via MFMA; one 16-w tile per wave ----
  {
    const int r = lane & 15, q = lane >> 4;

    short8 az[2];
    {
      const int w = wave * 16 + r;
      const int sz = ((w >> 2) ^ (w >> 5)) & 7;
      #pragma unroll
      for (int ksp = 0; ksp < 2; ++ksp) {
        const int kc = (ksp * 4 + q) ^ sz;
        az[ksp] = *(const short8*)&zT[w * 72 + kc * 8];
      }
    }
    short8 bw[4][2];
    #pragma unroll
    for (int nt = 0; nt < 4; ++nt) {
      const int o = nt * 16 + r;
      const int so = ((o >> 2) ^ (o >> 5)) & 7;
      #pragma unroll
      for (int ksp = 0; ksp < 2; ++ksp) {
        const int kc = (ksp * 4 + q) ^ so;
        bw[nt][ksp] = *(const short8*)&wt[o * 72 + kc * 8];
      }
    }

    floatx4 acc[4];
    #pragma unroll
    for (int nt = 0; nt < 4; ++nt) acc[nt] = (floatx4){0.f, 0.f, 0.f, 0.f};

    #pragma unroll
    for (int nt = 0; nt < 4; ++nt)
      #pragma unroll
      for (int ksp = 0; ksp < 2; ++ksp)
        acc[nt] = __builtin_amdgcn_mfma_f32_16x16x32_bf16(
            az[ksp], bw[nt][ksp], acc[nt], 0, 0, 0);

    const int wb = wave * 16 + q * 4;
    #pragma unroll
    for (int nt = 0; nt < 4; ++nt) {
      const int o = nt * 16 + r;
      const size_t off = base_b + (size_t)o * 16384 + (size_t)h * 128 + wb;
      float4 fv = *(const float4*)(feat + off);
      const float at = atts[o], bo = bcs[o];
      floatx4 a = acc[nt];
      float4 ov;
      ov.x = a[0] + bo + at * fv.x;
      ov.y = a[1] + bo + at * fv.y;
      ov.z = a[2] + bo + at * fv.z;
      ov.w = a[3] + bo + at * fv.w;
      *(float4*)(out + off) = ov;
    }
  }
}

extern "C" void kernel_launch(void* const* d_in, const int* in_sizes, int n_in,
                              void* d_out, int out_size, void* d_ws, size_t ws_size,
                              hipStream_t stream) {
  const float* feat   = (const float*)d_in[0];
  const float* deg    = (const float*)d_in[1];
  const float* W_size = (const float*)d_in[2];
  const float* W_k1   = (const float*)d_in[3];
  const float* W_k2   = (const float*)d_in[4];
  const float* W_conv = (const float*)d_in[5];
  const float* b_conv = (const float*)d_in[6];
  const float* W_ac   = (const float*)d_in[7];
  const float* W_du1  = (const float*)d_in[8];
  const float* W_du2  = (const float*)d_in[9];
  float* out = (float*)d_out;

  float* kern_ws = (float*)d_ws;            // 16*576 = 9216 f
  float* att_ws  = kern_ws + 16 * 576;      // 16*64  = 1024 f
  float* dvec_ws = att_ws + 16 * 64;        // 16*512 = 8192 f
  float* f_ws    = dvec_ws + 16 * 512;      // 16*64  = 1024 f
  float* fa_ws   = f_ws + 16 * 64;          // 16*64  = 1024 f

  prep_dvec<<<64, 256, 0, stream>>>(deg, dvec_ws);
  prep_fmul<<<128, 256, 0, stream>>>(W_size, W_ac, dvec_ws, f_ws, fa_ws);
  prep_tail<<<16, 256, 0, stream>>>(W_k1, W_k2, W_du1, W_du2, f_ws, fa_ws,
                                    kern_ws, att_ws);
  fused_kernel<<<2048, 512, 0, stream>>>(feat, W_conv, b_conv, kern_ws, att_ws,
                                         out);
}